// Round 3
// baseline (146.299 us; speedup 1.0000x reference)
//
#include <hip/hip_runtime.h>

#define D     128
#define DP1   129
#define KN    10
#define GSZ   100000.0f

typedef __attribute__((ext_vector_type(8))) short bf16x8;
typedef __attribute__((ext_vector_type(4))) float f32x4;

#define MFMA16(a, b, c) __builtin_amdgcn_mfma_f32_16x16x32_bf16((a), (b), (c), 0, 0, 0)

__device__ __forceinline__ float sigmoidf_(float x) {
    return 1.0f / (1.0f + __expf(-x));
}
__device__ __forceinline__ unsigned short f2bf(float f) {
    unsigned u = __float_as_uint(f);
    u += 0x7FFFu + ((u >> 16) & 1u);          // RNE
    return (unsigned short)(u >> 16);
}
__device__ __forceinline__ unsigned pack2bf(float lo, float hi) {
    return (unsigned)f2bf(lo) | ((unsigned)f2bf(hi) << 16);
}

// ---------------------------------------------------------------------------
// Kernel 1: per-seed SAGE row -> srow[b][128] (no atomics, pad writes zero)
// ---------------------------------------------------------------------------
__global__ __launch_bounds__(128) void seed_kernel(
    const int*   __restrict__ seeds,
    const int*   __restrict__ all_nodes,
    const float* __restrict__ mask,
    const float* __restrict__ features,
    const int*   __restrict__ neigh,
    const float* __restrict__ Wself,
    const float* __restrict__ Wneigh,
    float*       __restrict__ srow,
    int N)
{
    const int t = threadIdx.x;
    const int node = seeds[blockIdx.x];
    if (node >= N || node < 0) {              // pad row -> zero contribution
        srow[blockIdx.x * D + t] = 0.f;
        return;
    }

    __shared__ float xs[D], nb[D];
    xs[t] = features[(size_t)all_nodes[node] * D + t];
    float a = 0.f;
    #pragma unroll
    for (int k = 0; k < KN; ++k)
        a += features[(size_t)neigh[node * KN + k] * D + t];
    nb[t] = a * (1.0f / KN);
    __syncthreads();

    float h = 0.f;
    #pragma unroll 4
    for (int dp = 0; dp < D; ++dp)
        h = fmaf(xs[dp], Wself[dp * D + t], fmaf(nb[dp], Wneigh[dp * D + t], h));
    srow[blockIdx.x * D + t] = fmaxf(h, 0.f) * mask[node];
}

// ---------------------------------------------------------------------------
// Kernel 2: smp[144] = sigmoid((sum_b srow[b] / num) @ W1), zero-padded
// ---------------------------------------------------------------------------
__global__ __launch_bounds__(256) void sm_kernel(
    const float* __restrict__ srow, int S,
    const float* __restrict__ snum,
    const float* __restrict__ W1,
    float*       __restrict__ smp)
{
    __shared__ float s[D];
    const int t = threadIdx.x;
    if (t < D) {
        float a = 0.f;
        for (int b = 0; b < S; ++b) a += srow[b * D + t];
        s[t] = a / snum[0];
    }
    __syncthreads();
    if (t < DP1) {
        float a = 0.f;
        #pragma unroll 4
        for (int dp = 0; dp < D; ++dp)
            a = fmaf(s[dp], W1[dp * DP1 + t], a);
        smp[t] = sigmoidf_(a);
    } else if (t < 144) {
        smp[t] = 0.0f;
    }
}

// ---------------------------------------------------------------------------
// Kernel 3: gather + neighbor-mean -> dense xnb[Cpad][256] bf16, cmask[Cpad].
// One candidate per wave; every feature-row read is wave-coalesced (512 B).
// Tail blocks (>= nCandBlk) build W2T[128][256] and W3T[144][128] in bf16.
// ---------------------------------------------------------------------------
__global__ __launch_bounds__(256) void gather_kernel(
    const int*   __restrict__ cand,
    const int*   __restrict__ all_nodes,
    const float* __restrict__ mask,
    const float* __restrict__ features,
    const int*   __restrict__ neigh,
    const float* __restrict__ Wself,
    const float* __restrict__ Wneigh,
    const float* __restrict__ W3,
    unsigned*       __restrict__ xnb,     // as uint (2 bf16 each)
    float*          __restrict__ cmask,
    unsigned short* __restrict__ W2T,
    unsigned short* __restrict__ W3T,
    int C, int nCandBlk)
{
    if (blockIdx.x >= nCandBlk) {
        // ---- weight prep tail ----
        int t = (blockIdx.x - nCandBlk) * 256 + threadIdx.x;
        if (t < 128 * 256) {
            int n = t >> 8, k = t & 255;
            float v = (k < 128) ? Wself[k * 128 + n] : Wneigh[(k - 128) * 128 + n];
            W2T[n * 256 + k] = f2bf(v);
        } else {
            int u = t - 128 * 256;
            if (u < 144 * 128) {
                int j = u >> 7, k = u & 127;
                float v = (j < DP1) ? W3[k * DP1 + j] : 0.0f;
                W3T[j * 128 + k] = f2bf(v);
            }
        }
        return;
    }

    const int lane = threadIdx.x & 63;
    const int wv   = threadIdx.x >> 6;
    const int c    = blockIdx.x * 4 + wv;

    if (c >= C) {                  // pad candidate -> zero row
        xnb[(size_t)c * 128 + lane]      = 0u;
        xnb[(size_t)c * 128 + 64 + lane] = 0u;
        if (lane == 0) cmask[c] = 0.f;
        return;
    }

    const int node = cand[c];
    const int frow = all_nodes[node];

    const float2 xv = *(const float2*)(features + (size_t)frow * D + 2 * lane);

    int idx[KN];
    const int* nr = neigh + node * KN;
    #pragma unroll
    for (int k = 0; k < KN; ++k) idx[k] = nr[k];

    float a0 = 0.f, a1 = 0.f;
    #pragma unroll
    for (int k = 0; k < KN; ++k) {
        const float2 v = *(const float2*)(features + (size_t)idx[k] * D + 2 * lane);
        a0 += v.x; a1 += v.y;
    }

    xnb[(size_t)c * 128 + lane]      = pack2bf(xv.x, xv.y);
    xnb[(size_t)c * 128 + 64 + lane] = pack2bf(a0 * (1.0f / KN), a1 * (1.0f / KN));
    if (lane == 0) cmask[c] = mask[node];
}

// ---------------------------------------------------------------------------
// Kernel 4: dense MFMA. 256 thr = 4 waves; 16 cands/wave, 64/block.
// GEMM1: [16 x 256] @ W2T -> h[16][128]; GEMM2: h @ W3T -> S[16][144];
// epilogue: Q = (1 - sum_j smp[j]*sigmoid(S[.][j])) * GSZ.
// ---------------------------------------------------------------------------
__global__ __launch_bounds__(256) void gemm_kernel(
    const unsigned short* __restrict__ xnb,
    const float*          __restrict__ cmask,
    const unsigned short* __restrict__ W2T,
    const unsigned short* __restrict__ W3T,
    const float*          __restrict__ smp,
    float*                __restrict__ Q,
    int C)
{
    const int lane = threadIdx.x & 63;
    const int wv   = threadIdx.x >> 6;
    const int g    = lane >> 4;
    const int n15  = lane & 15;
    const int cbase = blockIdx.x * 64 + wv * 16;
    const int row   = cbase + n15;

    // ---- dense A fragments ----
    bf16x8 a[8];
    {
        const unsigned short* ap = xnb + (size_t)row * 256 + g * 8;
        #pragma unroll
        for (int ks = 0; ks < 8; ++ks)
            a[ks] = *(const bf16x8*)(ap + ks * 32);
    }

    // ---- GEMM1: K=256, N=128 ----
    f32x4 acc1[8];
    #pragma unroll
    for (int nt = 0; nt < 8; ++nt) acc1[nt] = (f32x4){0.f, 0.f, 0.f, 0.f};

    #pragma unroll
    for (int ks = 0; ks < 8; ++ks) {
        const unsigned short* bp = W2T + n15 * 256 + ks * 32 + g * 8;
        #pragma unroll
        for (int nt = 0; nt < 8; ++nt) {
            const bf16x8 b = *(const bf16x8*)(bp + nt * 16 * 256);
            acc1[nt] = MFMA16(a[ks], b, acc1[nt]);
        }
    }

    // ---- relu * mask -> LDS (layout change) ----
    float mrow[4];
    #pragma unroll
    for (int r = 0; r < 4; ++r) mrow[r] = cmask[cbase + g * 4 + r];

    __shared__ float hl[4][16][132];
    #pragma unroll
    for (int nt = 0; nt < 8; ++nt) {
        const f32x4 v = acc1[nt];
        #pragma unroll
        for (int r = 0; r < 4; ++r)
            hl[wv][g * 4 + r][nt * 16 + n15] = fmaxf(v[r], 0.f) * mrow[r];
    }
    __syncthreads();

    // ---- read h back as A-fragments ----
    bf16x8 ah[4];
    #pragma unroll
    for (int ks = 0; ks < 4; ++ks) {
        const float* p = &hl[wv][n15][ks * 32 + g * 8];
        const f32x4 lo = *(const f32x4*)p;
        const f32x4 hi = *(const f32x4*)(p + 4);
        #pragma unroll
        for (int j = 0; j < 4; ++j) {
            ah[ks][j]     = (short)f2bf(lo[j]);
            ah[ks][4 + j] = (short)f2bf(hi[j]);
        }
    }

    // ---- GEMM2: h[16x128] @ W3pad[128x144] ----
    f32x4 acc2[9];
    #pragma unroll
    for (int jt = 0; jt < 9; ++jt) acc2[jt] = (f32x4){0.f, 0.f, 0.f, 0.f};

    #pragma unroll
    for (int ks = 0; ks < 4; ++ks) {
        const unsigned short* bp = W3T + n15 * 128 + ks * 32 + g * 8;
        #pragma unroll
        for (int jt = 0; jt < 9; ++jt) {
            const bf16x8 b = *(const bf16x8*)(bp + jt * 16 * 128);
            acc2[jt] = MFMA16(ah[ks], b, acc2[jt]);
        }
    }

    // ---- epilogue ----
    float qp[4] = {0.f, 0.f, 0.f, 0.f};
    #pragma unroll
    for (int jt = 0; jt < 9; ++jt) {
        const float smj = smp[jt * 16 + n15];
        const f32x4 v = acc2[jt];
        #pragma unroll
        for (int r = 0; r < 4; ++r)
            qp[r] += smj * sigmoidf_(v[r]);
    }
    #pragma unroll
    for (int off = 8; off >= 1; off >>= 1)
        #pragma unroll
        for (int r = 0; r < 4; ++r)
            qp[r] += __shfl_xor(qp[r], off);

    if (n15 == 0) {
        #pragma unroll
        for (int r = 0; r < 4; ++r) {
            const int cr = cbase + g * 4 + r;
            if (cr < C) Q[cr] = (1.0f - qp[r]) * GSZ;
        }
    }
}

// ---------------------------------------------------------------------------
// Fallback fp32 candidate kernel (used only if ws too small)
// ---------------------------------------------------------------------------
#define MCAND 8
__global__ __launch_bounds__(128) void cand_kernel(
    const int*   __restrict__ cand,
    const int*   __restrict__ all_nodes,
    const float* __restrict__ mask,
    const float* __restrict__ features,
    const int*   __restrict__ neigh,
    const float* __restrict__ Wself,
    const float* __restrict__ Wneigh,
    const float* __restrict__ W3,
    const float* __restrict__ sm,
    float*       __restrict__ Q,
    int C)
{
    const int c0 = blockIdx.x * MCAND;
    const int t  = threadIdx.x;

    __shared__ float z[2 * MCAND][D];
    __shared__ float h[MCAND][D];
    __shared__ float red1[MCAND][D];
    __shared__ float red2[MCAND][D];
    __shared__ float smsh[DP1];

    smsh[t] = sm[t];
    if (t == 0) smsh[D] = sm[D];

    float msk[MCAND];
    #pragma unroll
    for (int m = 0; m < MCAND; ++m) {
        const int c    = c0 + m;
        const int node = (c < C) ? cand[c] : cand[0];
        msk[m] = mask[node];
        z[m][t] = features[(size_t)all_nodes[node] * D + t];
        float a = 0.f;
        #pragma unroll
        for (int k = 0; k < KN; ++k)
            a += features[(size_t)neigh[node * KN + k] * D + t];
        z[MCAND + m][t] = a * (1.0f / KN);
    }
    __syncthreads();

    float acc[MCAND];
    #pragma unroll
    for (int m = 0; m < MCAND; ++m) acc[m] = 0.f;
    for (int dp = 0; dp < D; dp += 4) {
        const float ws0 = Wself[(dp + 0) * D + t];
        const float ws1 = Wself[(dp + 1) * D + t];
        const float ws2 = Wself[(dp + 2) * D + t];
        const float ws3 = Wself[(dp + 3) * D + t];
        const float wn0 = Wneigh[(dp + 0) * D + t];
        const float wn1 = Wneigh[(dp + 1) * D + t];
        const float wn2 = Wneigh[(dp + 2) * D + t];
        const float wn3 = Wneigh[(dp + 3) * D + t];
        #pragma unroll
        for (int m = 0; m < MCAND; ++m) {
            const float4 xv = *(const float4*)&z[m][dp];
            const float4 nv = *(const float4*)&z[MCAND + m][dp];
            float a = acc[m];
            a = fmaf(xv.x, ws0, a); a = fmaf(xv.y, ws1, a);
            a = fmaf(xv.z, ws2, a); a = fmaf(xv.w, ws3, a);
            a = fmaf(nv.x, wn0, a); a = fmaf(nv.y, wn1, a);
            a = fmaf(nv.z, wn2, a); a = fmaf(nv.w, wn3, a);
            acc[m] = a;
        }
    }
    #pragma unroll
    for (int m = 0; m < MCAND; ++m)
        h[m][t] = fmaxf(acc[m], 0.f) * msk[m];
    __syncthreads();

    #pragma unroll
    for (int m = 0; m < MCAND; ++m) acc[m] = 0.f;
    for (int dp = 0; dp < D; dp += 4) {
        const float w0 = W3[(dp + 0) * DP1 + t];
        const float w1 = W3[(dp + 1) * DP1 + t];
        const float w2 = W3[(dp + 2) * DP1 + t];
        const float w3 = W3[(dp + 3) * DP1 + t];
        #pragma unroll
        for (int m = 0; m < MCAND; ++m) {
            const float4 hv = *(const float4*)&h[m][dp];
            float a = acc[m];
            a = fmaf(hv.x, w0, a); a = fmaf(hv.y, w1, a);
            a = fmaf(hv.z, w2, a); a = fmaf(hv.w, w3, a);
            acc[m] = a;
        }
    }

    const float w128 = W3[t * DP1 + D];
    const float smt  = smsh[t];
    #pragma unroll
    for (int m = 0; m < MCAND; ++m) {
        red1[m][t] = smt * sigmoidf_(acc[m]);
        red2[m][t] = h[m][t] * w128;
    }
    __syncthreads();

    for (int off = 64; off > 0; off >>= 1) {
        if (t < off) {
            #pragma unroll
            for (int m = 0; m < MCAND; ++m) {
                red1[m][t] += red1[m][t + off];
                red2[m][t] += red2[m][t + off];
            }
        }
        __syncthreads();
    }

    if (t < MCAND && (c0 + t) < C) {
        const float dot = red1[t][0] + smsh[D] * sigmoidf_(red2[t][0]);
        Q[c0 + t] = (1.0f - dot) * GSZ;
    }
}

// ---------------------------------------------------------------------------
extern "C" void kernel_launch(void* const* d_in, const int* in_sizes, int n_in,
                              void* d_out, int out_size, void* d_ws, size_t ws_size,
                              hipStream_t stream)
{
    const int*   seeds    = (const int*)  d_in[0];
    const float* snum     = (const float*)d_in[1];
    const int*   cand     = (const int*)  d_in[2];
    const int*   allnodes = (const int*)  d_in[3];
    const float* mask     = (const float*)d_in[4];
    const float* features = (const float*)d_in[5];
    const int*   neigh    = (const int*)  d_in[6];
    const float* Wself    = (const float*)d_in[7];
    const float* Wneigh   = (const float*)d_in[8];
    const float* W1       = (const float*)d_in[9];
    // d_in[10] = W2 : unused in reference
    const float* W3       = (const float*)d_in[11];

    float* Q = (float*)d_out;

    const int S = in_sizes[0];
    const int C = in_sizes[2];
    const int N = in_sizes[3];
    const int Cpad = ((C + 63) / 64) * 64;

    // ws layout (bytes)
    char* ws = (char*)d_ws;
    float*          srow  = (float*)ws;                    // S*128 f32
    float*          smp   = (float*)(ws + 57344);          // 144 f32
    unsigned short* W2T   = (unsigned short*)(ws + 65536); // 64 KB
    unsigned short* W3T   = (unsigned short*)(ws + 131072);// 36 KB
    float*          cmask = (float*)(ws + 167936);         // Cpad f32
    size_t xnb_off = 167936 + (size_t)Cpad * 4;
    xnb_off = (xnb_off + 511) & ~(size_t)511;
    unsigned*       xnb   = (unsigned*)(ws + xnb_off);     // Cpad*256 bf16
    const size_t need = xnb_off + (size_t)Cpad * 256 * 2;

    seed_kernel<<<S, 128, 0, stream>>>(seeds, allnodes, mask, features, neigh,
                                       Wself, Wneigh, srow, N);
    sm_kernel<<<1, 256, 0, stream>>>(srow, S, snum, W1, smp);

    if (ws_size >= need && (size_t)S * D * 4 <= 57344) {
        const int nCandBlk = Cpad / 4;
        const int nPrepBlk = (128 * 256 + 144 * 128 + 255) / 256;
        gather_kernel<<<nCandBlk + nPrepBlk, 256, 0, stream>>>(
            cand, allnodes, mask, features, neigh, Wself, Wneigh, W3,
            xnb, cmask, W2T, W3T, C, nCandBlk);
        gemm_kernel<<<Cpad / 64, 256, 0, stream>>>(
            (const unsigned short*)xnb, cmask, W2T, W3T, smp, Q, C);
    } else {
        const int nblk = (C + MCAND - 1) / MCAND;
        cand_kernel<<<nblk, 128, 0, stream>>>(cand, allnodes, mask, features,
                                              neigh, Wself, Wneigh, W3, smp, Q, C);
    }
}

// Round 4
// 136.533 us; speedup vs baseline: 1.0715x; 1.0715x over previous
//
#include <hip/hip_runtime.h>

#define D     128
#define DP1   129
#define KN    10
#define GSZ   100000.0f

typedef __attribute__((ext_vector_type(8))) short bf16x8;
typedef __attribute__((ext_vector_type(4))) float f32x4;

#define MFMA16(a, b, c) __builtin_amdgcn_mfma_f32_16x16x32_bf16((a), (b), (c), 0, 0, 0)

__device__ __forceinline__ float sigmoidf_(float x) {
    return 1.0f / (1.0f + __expf(-x));
}
__device__ __forceinline__ unsigned short f2bf(float f) {
    unsigned u = __float_as_uint(f);
    u += 0x7FFFu + ((u >> 16) & 1u);          // RNE
    return (unsigned short)(u >> 16);
}
__device__ __forceinline__ unsigned pack2bf(float lo, float hi) {
    return (unsigned)f2bf(lo) | ((unsigned)f2bf(hi) << 16);
}

// ---------------------------------------------------------------------------
// Kernel 1: per-seed SAGE row -> srow[b][128] (no atomics, pad writes zero)
// ---------------------------------------------------------------------------
__global__ __launch_bounds__(128) void seed_kernel(
    const int*   __restrict__ seeds,
    const int*   __restrict__ all_nodes,
    const float* __restrict__ mask,
    const float* __restrict__ features,
    const int*   __restrict__ neigh,
    const float* __restrict__ Wself,
    const float* __restrict__ Wneigh,
    float*       __restrict__ srow,
    int N)
{
    const int t = threadIdx.x;
    const int node = seeds[blockIdx.x];
    if (node >= N || node < 0) {              // pad row -> zero contribution
        srow[blockIdx.x * D + t] = 0.f;
        return;
    }

    __shared__ float xs[D], nb[D];
    xs[t] = features[(size_t)all_nodes[node] * D + t];
    float a = 0.f;
    #pragma unroll
    for (int k = 0; k < KN; ++k)
        a += features[(size_t)neigh[node * KN + k] * D + t];
    nb[t] = a * (1.0f / KN);
    __syncthreads();

    float h = 0.f;
    #pragma unroll 4
    for (int dp = 0; dp < D; ++dp)
        h = fmaf(xs[dp], Wself[dp * D + t], fmaf(nb[dp], Wneigh[dp * D + t], h));
    srow[blockIdx.x * D + t] = fmaxf(h, 0.f) * mask[node];
}

// ---------------------------------------------------------------------------
// Kernel 2: bf16 weight prep: W2T[128][256] = [Wself;Wneigh]^T,
//           W3T[144][128] = padded W3^T.   51200 elems, 200 blocks.
// ---------------------------------------------------------------------------
__global__ __launch_bounds__(256) void wprep_kernel(
    const float* __restrict__ Wself, const float* __restrict__ Wneigh,
    const float* __restrict__ W3,
    unsigned short* __restrict__ W2T, unsigned short* __restrict__ W3T)
{
    int t = blockIdx.x * 256 + threadIdx.x;
    if (t < 128 * 256) {
        int n = t >> 8, k = t & 255;
        float v = (k < 128) ? Wself[k * 128 + n] : Wneigh[(k - 128) * 128 + n];
        W2T[n * 256 + k] = f2bf(v);
    } else {
        int u = t - 128 * 256;
        if (u < 144 * 128) {
            int j = u >> 7, k = u & 127;
            float v = (j < DP1) ? W3[k * DP1 + j] : 0.0f;
            W3T[j * 128 + k] = f2bf(v);
        }
    }
}

// ---------------------------------------------------------------------------
// Kernel 3: smp[144] = sigmoid((sum_b srow[b] / num) @ W1), zero-padded
// ---------------------------------------------------------------------------
__global__ __launch_bounds__(256) void sm_kernel(
    const float* __restrict__ srow, int S,
    const float* __restrict__ snum,
    const float* __restrict__ W1,
    float*       __restrict__ smp)
{
    __shared__ float s[D];
    const int t = threadIdx.x;
    if (t < D) {
        float a = 0.f;
        for (int b = 0; b < S; ++b) a += srow[b * D + t];
        s[t] = a / snum[0];
    }
    __syncthreads();
    if (t < DP1) {
        float a = 0.f;
        #pragma unroll 4
        for (int dp = 0; dp < D; ++dp)
            a = fmaf(s[dp], W1[dp * DP1 + t], a);
        smp[t] = sigmoidf_(a);
    } else if (t < 144) {
        smp[t] = 0.0f;
    }
}

// ---------------------------------------------------------------------------
// Kernel 4: FUSED gather + GEMM1 + GEMM2 + epilogue.
// 256 thr = 4 waves; one 16-candidate tile per wave; no __syncthreads.
// Per-wave private LDS tile [16][256] bf16, XOR-swizzled ((row&7)<<3 shorts).
// ---------------------------------------------------------------------------
__global__ __launch_bounds__(256, 3) void fused_kernel(
    const int*            __restrict__ cand,
    const int*            __restrict__ all_nodes,
    const float*          __restrict__ mask,
    const float*          __restrict__ features,
    const int*            __restrict__ neigh,
    const unsigned short* __restrict__ W2T,
    const unsigned short* __restrict__ W3T,
    const float*          __restrict__ smp,
    float*                __restrict__ Q,
    int C, int nTiles)
{
    __shared__ unsigned short tile[4][16][256];

    const int lane = threadIdx.x & 63;
    const int wv   = __builtin_amdgcn_readfirstlane(threadIdx.x >> 6);
    const int T    = blockIdx.x * 4 + wv;
    if (T >= nTiles) return;

    const int g     = lane >> 4;
    const int n15   = lane & 15;
    const int cbase = T * 16;
    unsigned short* tp = &tile[wv][0][0];

    // ---- gather: 16 x (1 + 10) wave-coalesced 512B row loads ----
    float2 xx[16], aa[16];
    #pragma unroll
    for (int m = 0; m < 16; ++m) {
        const int cc = cbase + m;                 // wave-uniform -> s_load chain
        const int nd = cand[(cc < C) ? cc : 0];
        const int fr = all_nodes[nd];
        xx[m] = *(const float2*)(features + (size_t)fr * D + lane * 2);
        const int* nr = neigh + nd * KN;
        float ax = 0.f, ay = 0.f;
        #pragma unroll
        for (int k = 0; k < KN; ++k) {
            const float2 v = *(const float2*)(features + (size_t)nr[k] * D + lane * 2);
            ax += v.x; ay += v.y;
        }
        aa[m].x = ax; aa[m].y = ay;
    }

    // ---- pack to bf16 tile (swizzled) ----
    #pragma unroll
    for (int m = 0; m < 16; ++m) {
        const int sw = (m & 7) << 3;
        *(unsigned*)(tp + m * 256 + ((lane * 2) ^ sw)) = pack2bf(xx[m].x, xx[m].y);
        *(unsigned*)(tp + m * 256 + ((128 + lane * 2) ^ sw)) =
            pack2bf(aa[m].x * (1.0f / KN), aa[m].y * (1.0f / KN));
    }

    // ---- A fragments (row = n15, k-slice = ks*32 + g*8) ----
    const int swr = (n15 & 7) << 3;
    bf16x8 afr[8];
    #pragma unroll
    for (int ks = 0; ks < 8; ++ks)
        afr[ks] = *(const bf16x8*)(tp + n15 * 256 + ((ks * 32 + g * 8) ^ swr));

    // ---- GEMM1: [16 x 256] @ W2T -> h[16][128] ----
    f32x4 acc1[8];
    #pragma unroll
    for (int nt = 0; nt < 8; ++nt) acc1[nt] = (f32x4){0.f, 0.f, 0.f, 0.f};

    #pragma unroll
    for (int ks = 0; ks < 8; ++ks) {
        const unsigned short* bp = W2T + n15 * 256 + ks * 32 + g * 8;
        #pragma unroll
        for (int nt = 0; nt < 8; ++nt) {
            const bf16x8 b = *(const bf16x8*)(bp + nt * 16 * 256);
            acc1[nt] = MFMA16(afr[ks], b, acc1[nt]);
        }
    }

    // ---- relu * mask -> bf16 back into same tile (cols 0..127) ----
    float mrow[4];
    #pragma unroll
    for (int r = 0; r < 4; ++r) {
        const int cr = cbase + g * 4 + r;
        mrow[r] = (cr < C) ? mask[cand[cr]] : 0.f;
    }
    #pragma unroll
    for (int nt = 0; nt < 8; ++nt) {
        const f32x4 v = acc1[nt];
        #pragma unroll
        for (int r = 0; r < 4; ++r) {
            const int m2 = g * 4 + r;
            tp[m2 * 256 + ((nt * 16 + n15) ^ ((m2 & 7) << 3))] =
                f2bf(fmaxf(v[r], 0.f) * mrow[r]);
        }
    }

    // ---- read h back as A-fragments ----
    bf16x8 ah[4];
    #pragma unroll
    for (int ks = 0; ks < 4; ++ks)
        ah[ks] = *(const bf16x8*)(tp + n15 * 256 + ((ks * 32 + g * 8) ^ swr));

    // ---- GEMM2: h[16x128] @ W3pad[128x144] ----
    f32x4 acc2[9];
    #pragma unroll
    for (int jt = 0; jt < 9; ++jt) acc2[jt] = (f32x4){0.f, 0.f, 0.f, 0.f};

    #pragma unroll
    for (int ks = 0; ks < 4; ++ks) {
        const unsigned short* bp = W3T + n15 * 128 + ks * 32 + g * 8;
        #pragma unroll
        for (int jt = 0; jt < 9; ++jt) {
            const bf16x8 b = *(const bf16x8*)(bp + jt * 16 * 128);
            acc2[jt] = MFMA16(ah[ks], b, acc2[jt]);
        }
    }

    // ---- epilogue: q[m] = sum_j smp[j] * sigmoid(S[m][j]) ----
    float qp[4] = {0.f, 0.f, 0.f, 0.f};
    #pragma unroll
    for (int jt = 0; jt < 9; ++jt) {
        const float smj = smp[jt * 16 + n15];
        const f32x4 v = acc2[jt];
        #pragma unroll
        for (int r = 0; r < 4; ++r)
            qp[r] += smj * sigmoidf_(v[r]);
    }
    #pragma unroll
    for (int off = 8; off >= 1; off >>= 1)
        #pragma unroll
        for (int r = 0; r < 4; ++r)
            qp[r] += __shfl_xor(qp[r], off);

    if (n15 == 0) {
        #pragma unroll
        for (int r = 0; r < 4; ++r) {
            const int cr = cbase + g * 4 + r;
            if (cr < C) Q[cr] = (1.0f - qp[r]) * GSZ;
        }
    }
}

// ---------------------------------------------------------------------------
// Fallback fp32 candidate kernel (used only if ws too small)
// ---------------------------------------------------------------------------
#define MCAND 8
__global__ __launch_bounds__(128) void cand_kernel(
    const int*   __restrict__ cand,
    const int*   __restrict__ all_nodes,
    const float* __restrict__ mask,
    const float* __restrict__ features,
    const int*   __restrict__ neigh,
    const float* __restrict__ Wself,
    const float* __restrict__ Wneigh,
    const float* __restrict__ W3,
    const float* __restrict__ sm,
    float*       __restrict__ Q,
    int C)
{
    const int c0 = blockIdx.x * MCAND;
    const int t  = threadIdx.x;

    __shared__ float z[2 * MCAND][D];
    __shared__ float h[MCAND][D];
    __shared__ float red1[MCAND][D];
    __shared__ float red2[MCAND][D];
    __shared__ float smsh[DP1];

    smsh[t] = sm[t];
    if (t == 0) smsh[D] = sm[D];

    float msk[MCAND];
    #pragma unroll
    for (int m = 0; m < MCAND; ++m) {
        const int c    = c0 + m;
        const int node = (c < C) ? cand[c] : cand[0];
        msk[m] = mask[node];
        z[m][t] = features[(size_t)all_nodes[node] * D + t];
        float a = 0.f;
        #pragma unroll
        for (int k = 0; k < KN; ++k)
            a += features[(size_t)neigh[node * KN + k] * D + t];
        z[MCAND + m][t] = a * (1.0f / KN);
    }
    __syncthreads();

    float acc[MCAND];
    #pragma unroll
    for (int m = 0; m < MCAND; ++m) acc[m] = 0.f;
    for (int dp = 0; dp < D; dp += 4) {
        const float ws0 = Wself[(dp + 0) * D + t];
        const float ws1 = Wself[(dp + 1) * D + t];
        const float ws2 = Wself[(dp + 2) * D + t];
        const float ws3 = Wself[(dp + 3) * D + t];
        const float wn0 = Wneigh[(dp + 0) * D + t];
        const float wn1 = Wneigh[(dp + 1) * D + t];
        const float wn2 = Wneigh[(dp + 2) * D + t];
        const float wn3 = Wneigh[(dp + 3) * D + t];
        #pragma unroll
        for (int m = 0; m < MCAND; ++m) {
            const float4 xv = *(const float4*)&z[m][dp];
            const float4 nv = *(const float4*)&z[MCAND + m][dp];
            float a = acc[m];
            a = fmaf(xv.x, ws0, a); a = fmaf(xv.y, ws1, a);
            a = fmaf(xv.z, ws2, a); a = fmaf(xv.w, ws3, a);
            a = fmaf(nv.x, wn0, a); a = fmaf(nv.y, wn1, a);
            a = fmaf(nv.z, wn2, a); a = fmaf(nv.w, wn3, a);
            acc[m] = a;
        }
    }
    #pragma unroll
    for (int m = 0; m < MCAND; ++m)
        h[m][t] = fmaxf(acc[m], 0.f) * msk[m];
    __syncthreads();

    #pragma unroll
    for (int m = 0; m < MCAND; ++m) acc[m] = 0.f;
    for (int dp = 0; dp < D; dp += 4) {
        const float w0 = W3[(dp + 0) * DP1 + t];
        const float w1 = W3[(dp + 1) * DP1 + t];
        const float w2 = W3[(dp + 2) * DP1 + t];
        const float w3 = W3[(dp + 3) * DP1 + t];
        #pragma unroll
        for (int m = 0; m < MCAND; ++m) {
            const float4 hv = *(const float4*)&h[m][dp];
            float a = acc[m];
            a = fmaf(hv.x, w0, a); a = fmaf(hv.y, w1, a);
            a = fmaf(hv.z, w2, a); a = fmaf(hv.w, w3, a);
            acc[m] = a;
        }
    }

    const float w128 = W3[t * DP1 + D];
    const float smt  = smsh[t];
    #pragma unroll
    for (int m = 0; m < MCAND; ++m) {
        red1[m][t] = smt * sigmoidf_(acc[m]);
        red2[m][t] = h[m][t] * w128;
    }
    __syncthreads();

    for (int off = 64; off > 0; off >>= 1) {
        if (t < off) {
            #pragma unroll
            for (int m = 0; m < MCAND; ++m) {
                red1[m][t] += red1[m][t + off];
                red2[m][t] += red2[m][t + off];
            }
        }
        __syncthreads();
    }

    if (t < MCAND && (c0 + t) < C) {
        const float dot = red1[t][0] + smsh[D] * sigmoidf_(red2[t][0]);
        Q[c0 + t] = (1.0f - dot) * GSZ;
    }
}

// ---------------------------------------------------------------------------
extern "C" void kernel_launch(void* const* d_in, const int* in_sizes, int n_in,
                              void* d_out, int out_size, void* d_ws, size_t ws_size,
                              hipStream_t stream)
{
    const int*   seeds    = (const int*)  d_in[0];
    const float* snum     = (const float*)d_in[1];
    const int*   cand     = (const int*)  d_in[2];
    const int*   allnodes = (const int*)  d_in[3];
    const float* mask     = (const float*)d_in[4];
    const float* features = (const float*)d_in[5];
    const int*   neigh    = (const int*)  d_in[6];
    const float* Wself    = (const float*)d_in[7];
    const float* Wneigh   = (const float*)d_in[8];
    const float* W1       = (const float*)d_in[9];
    // d_in[10] = W2 : unused in reference
    const float* W3       = (const float*)d_in[11];

    float* Q = (float*)d_out;

    const int S = in_sizes[0];
    const int C = in_sizes[2];
    const int N = in_sizes[3];

    // ws layout (bytes)
    char* ws = (char*)d_ws;
    float*          srow = (float*)ws;                     // S*128 f32 (<=56KB)
    float*          smp  = (float*)(ws + 57344);           // 144 f32
    unsigned short* W2T  = (unsigned short*)(ws + 65536);  // 64 KB
    unsigned short* W3T  = (unsigned short*)(ws + 131072); // 36 KB
    const size_t need = 131072 + 144 * 128 * 2;

    seed_kernel<<<S, 128, 0, stream>>>(seeds, allnodes, mask, features, neigh,
                                       Wself, Wneigh, srow, N);

    if (ws_size >= need && (size_t)S * D * 4 <= 57344) {
        wprep_kernel<<<200, 256, 0, stream>>>(Wself, Wneigh, W3, W2T, W3T);
        sm_kernel<<<1, 256, 0, stream>>>(srow, S, snum, W1, smp);
        const int nTiles = (C + 15) / 16;
        const int nBlk   = (nTiles + 3) / 4;
        fused_kernel<<<nBlk, 256, 0, stream>>>(cand, allnodes, mask, features,
                                               neigh, W2T, W3T, smp, Q, C, nTiles);
    } else {
        sm_kernel<<<1, 256, 0, stream>>>(srow, S, snum, W1, smp);
        const int nblk = (C + MCAND - 1) / MCAND;
        cand_kernel<<<nblk, 128, 0, stream>>>(cand, allnodes, mask, features,
                                              neigh, Wself, Wneigh, W3, smp, Q, C);
    }
}

// Round 5
// 108.796 us; speedup vs baseline: 1.3447x; 1.2549x over previous
//
#include <hip/hip_runtime.h>

#define D     128
#define DP1   129
#define KN    10
#define GSZ   100000.0f

typedef __attribute__((ext_vector_type(8))) short bf16x8;
typedef __attribute__((ext_vector_type(4))) float f32x4;

#define MFMA16(a, b, c) __builtin_amdgcn_mfma_f32_16x16x32_bf16((a), (b), (c), 0, 0, 0)

__device__ __forceinline__ float sigmoidf_(float x) {
    return 1.0f / (1.0f + __expf(-x));
}
__device__ __forceinline__ unsigned short f2bf(float f) {
    unsigned u = __float_as_uint(f);
    u += 0x7FFFu + ((u >> 16) & 1u);          // RNE
    return (unsigned short)(u >> 16);
}
__device__ __forceinline__ unsigned pack2bf(float lo, float hi) {
    return (unsigned)f2bf(lo) | ((unsigned)f2bf(hi) << 16);
}

// ---------------------------------------------------------------------------
// Prep kernel: three segments by blockIdx.
//   [0, nFeatBlk)        : features fp32 -> bf16 (featb)
//   [nFeatBlk, +200)     : W2T[128][256], W3T[144][128] bf16 transpose
//   [nFeatBlk+200, +S)   : per-seed SAGE row -> srow[b][128]
// With nFeatBlk==0 and grid==S+200 it still works (used by fallback too).
// ---------------------------------------------------------------------------
__global__ __launch_bounds__(256) void prep_kernel(
    const float* __restrict__ features,
    const float* __restrict__ Wself, const float* __restrict__ Wneigh,
    const float* __restrict__ W3,
    const int*   __restrict__ seeds,
    const int*   __restrict__ all_nodes,
    const float* __restrict__ mask,
    const int*   __restrict__ neigh,
    unsigned short* __restrict__ featb,
    unsigned short* __restrict__ W2T,
    unsigned short* __restrict__ W3T,
    float*          __restrict__ srow,
    int N, int nFeatBlk, int doW)
{
    int b = blockIdx.x;
    const int t = threadIdx.x;

    if (b < nFeatBlk) {
        const int i = b * 256 + t;                  // bf16x8 chunk
        const int n8 = N * D / 8;
        if (i < n8) {
            const float4 a = *(const float4*)(features + (size_t)i * 8);
            const float4 c = *(const float4*)(features + (size_t)i * 8 + 4);
            bf16x8 v;
            v[0] = (short)f2bf(a.x); v[1] = (short)f2bf(a.y);
            v[2] = (short)f2bf(a.z); v[3] = (short)f2bf(a.w);
            v[4] = (short)f2bf(c.x); v[5] = (short)f2bf(c.y);
            v[6] = (short)f2bf(c.z); v[7] = (short)f2bf(c.w);
            *(bf16x8*)(featb + (size_t)i * 8) = v;
        }
        return;
    }
    b -= nFeatBlk;

    if (b < doW * 200) {
        const int u = b * 256 + t;
        if (u < 128 * 256) {
            int n = u >> 8, k = u & 255;
            float v = (k < 128) ? Wself[k * 128 + n] : Wneigh[(k - 128) * 128 + n];
            W2T[n * 256 + k] = f2bf(v);
        } else {
            int w = u - 128 * 256;
            if (w < 144 * 128) {
                int j = w >> 7, k = w & 127;
                float v = (j < DP1) ? W3[k * DP1 + j] : 0.0f;
                W3T[j * 128 + k] = f2bf(v);
            }
        }
        return;
    }
    b -= doW * 200;

    // ---- seed segment (block b = seed slot) ----
    const int node = seeds[b];
    if (node >= N || node < 0) {                   // pad row -> zero
        if (t < D) srow[b * D + t] = 0.f;
        return;
    }
    __shared__ float xs[D], nb[D];
    if (t < D) {
        xs[t] = features[(size_t)all_nodes[node] * D + t];
        float a = 0.f;
        #pragma unroll
        for (int k = 0; k < KN; ++k)
            a += features[(size_t)neigh[node * KN + k] * D + t];
        nb[t] = a * (1.0f / KN);
    }
    __syncthreads();
    if (t < D) {
        float h = 0.f;
        #pragma unroll 4
        for (int dp = 0; dp < D; ++dp)
            h = fmaf(xs[dp], Wself[dp * D + t], fmaf(nb[dp], Wneigh[dp * D + t], h));
        srow[b * D + t] = fmaxf(h, 0.f) * mask[node];
    }
}

// ---------------------------------------------------------------------------
// sm kernel: smp[144] = sigmoid((sum_b srow[b] / num) @ W1), zero-padded
// ---------------------------------------------------------------------------
__global__ __launch_bounds__(256) void sm_kernel(
    const float* __restrict__ srow, int S,
    const float* __restrict__ snum,
    const float* __restrict__ W1,
    float*       __restrict__ smp)
{
    __shared__ float s[D];
    const int t = threadIdx.x;
    if (t < D) {
        float a = 0.f;
        for (int b = 0; b < S; ++b) a += srow[b * D + t];
        s[t] = a / snum[0];
    }
    __syncthreads();
    if (t < DP1) {
        float a = 0.f;
        #pragma unroll 4
        for (int dp = 0; dp < D; ++dp)
            a = fmaf(s[dp], W1[dp * DP1 + t], a);
        smp[t] = sigmoidf_(a);
    } else if (t < 144) {
        smp[t] = 0.0f;
    }
}

// ---------------------------------------------------------------------------
// Fused candidate kernel, cooperative-gather variant.
// One 16-cand tile per BLOCK; 4 waves gather 4 candidates each (bf16 rows,
// 256 B coalesced), one barrier, wave 0 runs GEMM1+GEMM2+epilogue.
// ---------------------------------------------------------------------------
__global__ __launch_bounds__(256, 4) void fused_kernel(
    const int*            __restrict__ cand,
    const int*            __restrict__ all_nodes,
    const float*          __restrict__ mask,
    const unsigned short* __restrict__ featb,
    const int*            __restrict__ neigh,
    const unsigned short* __restrict__ W2T,
    const unsigned short* __restrict__ W3T,
    const float*          __restrict__ smp,
    float*                __restrict__ Q,
    int C)
{
    __shared__ unsigned short tile[16][256];

    const int lane  = threadIdx.x & 63;
    const int wv    = threadIdx.x >> 6;
    const int cbase = blockIdx.x * 16;

    // ---- gather: wave wv owns candidates m = wv*4 .. wv*4+3 ----
    #pragma unroll
    for (int r = 0; r < 4; ++r) {
        const int m  = wv * 4 + r;
        const int cc = cbase + m;
        const int nd = cand[(cc < C) ? cc : 0];
        const int fr = all_nodes[nd];

        const unsigned xv = *(const unsigned*)(featb + (size_t)fr * D + lane * 2);

        const int* nr = neigh + nd * KN;
        float ax = 0.f, ay = 0.f;
        #pragma unroll
        for (int k = 0; k < KN; ++k) {
            const unsigned v = *(const unsigned*)(featb + (size_t)nr[k] * D + lane * 2);
            ax += __uint_as_float((v & 0xFFFFu) << 16);
            ay += __uint_as_float(v & 0xFFFF0000u);
        }

        const int sw = (m & 7) << 3;
        *(unsigned*)(&tile[m][(lane * 2) ^ sw])       = xv;
        *(unsigned*)(&tile[m][(128 + lane * 2) ^ sw]) =
            pack2bf(ax * (1.0f / KN), ay * (1.0f / KN));
    }
    __syncthreads();
    if (wv != 0) return;

    // ---- wave 0: GEMMs ----
    const int g   = lane >> 4;
    const int n15 = lane & 15;
    const unsigned short* tp = &tile[0][0];
    const int swr = (n15 & 7) << 3;

    bf16x8 afr[8];
    #pragma unroll
    for (int ks = 0; ks < 8; ++ks)
        afr[ks] = *(const bf16x8*)(tp + n15 * 256 + ((ks * 32 + g * 8) ^ swr));

    f32x4 acc1[8];
    #pragma unroll
    for (int nt = 0; nt < 8; ++nt) acc1[nt] = (f32x4){0.f, 0.f, 0.f, 0.f};

    #pragma unroll
    for (int ks = 0; ks < 8; ++ks) {
        const unsigned short* bp = W2T + n15 * 256 + ks * 32 + g * 8;
        #pragma unroll
        for (int nt = 0; nt < 8; ++nt) {
            const bf16x8 bfr = *(const bf16x8*)(bp + nt * 16 * 256);
            acc1[nt] = MFMA16(afr[ks], bfr, acc1[nt]);
        }
    }

    // relu * mask -> bf16 back into tile (cols 0..127)
    float mrow[4];
    #pragma unroll
    for (int r = 0; r < 4; ++r) {
        const int cr = cbase + g * 4 + r;
        mrow[r] = (cr < C) ? mask[cand[cr]] : 0.f;
    }
    #pragma unroll
    for (int nt = 0; nt < 8; ++nt) {
        const f32x4 v = acc1[nt];
        #pragma unroll
        for (int r = 0; r < 4; ++r) {
            const int m2 = g * 4 + r;
            tile[m2][(nt * 16 + n15) ^ ((m2 & 7) << 3)] =
                f2bf(fmaxf(v[r], 0.f) * mrow[r]);
        }
    }

    bf16x8 ah[4];
    #pragma unroll
    for (int ks = 0; ks < 4; ++ks)
        ah[ks] = *(const bf16x8*)(tp + n15 * 256 + ((ks * 32 + g * 8) ^ swr));

    f32x4 acc2[9];
    #pragma unroll
    for (int jt = 0; jt < 9; ++jt) acc2[jt] = (f32x4){0.f, 0.f, 0.f, 0.f};

    #pragma unroll
    for (int ks = 0; ks < 4; ++ks) {
        const unsigned short* bp = W3T + n15 * 128 + ks * 32 + g * 8;
        #pragma unroll
        for (int jt = 0; jt < 9; ++jt) {
            const bf16x8 bfr = *(const bf16x8*)(bp + jt * 16 * 128);
            acc2[jt] = MFMA16(ah[ks], bfr, acc2[jt]);
        }
    }

    float qp[4] = {0.f, 0.f, 0.f, 0.f};
    #pragma unroll
    for (int jt = 0; jt < 9; ++jt) {
        const float smj = smp[jt * 16 + n15];
        const f32x4 v = acc2[jt];
        #pragma unroll
        for (int r = 0; r < 4; ++r)
            qp[r] += smj * sigmoidf_(v[r]);
    }
    #pragma unroll
    for (int off = 8; off >= 1; off >>= 1)
        #pragma unroll
        for (int r = 0; r < 4; ++r)
            qp[r] += __shfl_xor(qp[r], off);

    if (n15 == 0) {
        #pragma unroll
        for (int r = 0; r < 4; ++r) {
            const int cr = cbase + g * 4 + r;
            if (cr < C) Q[cr] = (1.0f - qp[r]) * GSZ;
        }
    }
}

// ---------------------------------------------------------------------------
// Fallback fp32 candidate kernel (used only if ws too small)
// ---------------------------------------------------------------------------
#define MCAND 8
__global__ __launch_bounds__(128) void cand_kernel(
    const int*   __restrict__ cand,
    const int*   __restrict__ all_nodes,
    const float* __restrict__ mask,
    const float* __restrict__ features,
    const int*   __restrict__ neigh,
    const float* __restrict__ Wself,
    const float* __restrict__ Wneigh,
    const float* __restrict__ W3,
    const float* __restrict__ sm,
    float*       __restrict__ Q,
    int C)
{
    const int c0 = blockIdx.x * MCAND;
    const int t  = threadIdx.x;

    __shared__ float z[2 * MCAND][D];
    __shared__ float h[MCAND][D];
    __shared__ float red1[MCAND][D];
    __shared__ float red2[MCAND][D];
    __shared__ float smsh[DP1];

    smsh[t] = sm[t];
    if (t == 0) smsh[D] = sm[D];

    float msk[MCAND];
    #pragma unroll
    for (int m = 0; m < MCAND; ++m) {
        const int c    = c0 + m;
        const int node = (c < C) ? cand[c] : cand[0];
        msk[m] = mask[node];
        z[m][t] = features[(size_t)all_nodes[node] * D + t];
        float a = 0.f;
        #pragma unroll
        for (int k = 0; k < KN; ++k)
            a += features[(size_t)neigh[node * KN + k] * D + t];
        z[MCAND + m][t] = a * (1.0f / KN);
    }
    __syncthreads();

    float acc[MCAND];
    #pragma unroll
    for (int m = 0; m < MCAND; ++m) acc[m] = 0.f;
    for (int dp = 0; dp < D; dp += 4) {
        const float ws0 = Wself[(dp + 0) * D + t];
        const float ws1 = Wself[(dp + 1) * D + t];
        const float ws2 = Wself[(dp + 2) * D + t];
        const float ws3 = Wself[(dp + 3) * D + t];
        const float wn0 = Wneigh[(dp + 0) * D + t];
        const float wn1 = Wneigh[(dp + 1) * D + t];
        const float wn2 = Wneigh[(dp + 2) * D + t];
        const float wn3 = Wneigh[(dp + 3) * D + t];
        #pragma unroll
        for (int m = 0; m < MCAND; ++m) {
            const float4 xv = *(const float4*)&z[m][dp];
            const float4 nv = *(const float4*)&z[MCAND + m][dp];
            float a = acc[m];
            a = fmaf(xv.x, ws0, a); a = fmaf(xv.y, ws1, a);
            a = fmaf(xv.z, ws2, a); a = fmaf(xv.w, ws3, a);
            a = fmaf(nv.x, wn0, a); a = fmaf(nv.y, wn1, a);
            a = fmaf(nv.z, wn2, a); a = fmaf(nv.w, wn3, a);
            acc[m] = a;
        }
    }
    #pragma unroll
    for (int m = 0; m < MCAND; ++m)
        h[m][t] = fmaxf(acc[m], 0.f) * msk[m];
    __syncthreads();

    #pragma unroll
    for (int m = 0; m < MCAND; ++m) acc[m] = 0.f;
    for (int dp = 0; dp < D; dp += 4) {
        const float w0 = W3[(dp + 0) * DP1 + t];
        const float w1 = W3[(dp + 1) * DP1 + t];
        const float w2 = W3[(dp + 2) * DP1 + t];
        const float w3 = W3[(dp + 3) * DP1 + t];
        #pragma unroll
        for (int m = 0; m < MCAND; ++m) {
            const float4 hv = *(const float4*)&h[m][dp];
            float a = acc[m];
            a = fmaf(hv.x, w0, a); a = fmaf(hv.y, w1, a);
            a = fmaf(hv.z, w2, a); a = fmaf(hv.w, w3, a);
            acc[m] = a;
        }
    }

    const float w128 = W3[t * DP1 + D];
    const float smt  = smsh[t];
    #pragma unroll
    for (int m = 0; m < MCAND; ++m) {
        red1[m][t] = smt * sigmoidf_(acc[m]);
        red2[m][t] = h[m][t] * w128;
    }
    __syncthreads();

    for (int off = 64; off > 0; off >>= 1) {
        if (t < off) {
            #pragma unroll
            for (int m = 0; m < MCAND; ++m) {
                red1[m][t] += red1[m][t + off];
                red2[m][t] += red2[m][t + off];
            }
        }
        __syncthreads();
    }

    if (t < MCAND && (c0 + t) < C) {
        const float dot = red1[t][0] + smsh[D] * sigmoidf_(red2[t][0]);
        Q[c0 + t] = (1.0f - dot) * GSZ;
    }
}

// ---------------------------------------------------------------------------
extern "C" void kernel_launch(void* const* d_in, const int* in_sizes, int n_in,
                              void* d_out, int out_size, void* d_ws, size_t ws_size,
                              hipStream_t stream)
{
    const int*   seeds    = (const int*)  d_in[0];
    const float* snum     = (const float*)d_in[1];
    const int*   cand     = (const int*)  d_in[2];
    const int*   allnodes = (const int*)  d_in[3];
    const float* mask     = (const float*)d_in[4];
    const float* features = (const float*)d_in[5];
    const int*   neigh    = (const int*)  d_in[6];
    const float* Wself    = (const float*)d_in[7];
    const float* Wneigh   = (const float*)d_in[8];
    const float* W1       = (const float*)d_in[9];
    // d_in[10] = W2 : unused in reference
    const float* W3       = (const float*)d_in[11];

    float* Q = (float*)d_out;

    const int S = in_sizes[0];
    const int C = in_sizes[2];
    const int N = in_sizes[3];

    // ws layout (bytes)
    char* ws = (char*)d_ws;
    float*          srow  = (float*)ws;                     // S*128 f32 (<=56KB)
    float*          smp   = (float*)(ws + 57344);           // 144 f32
    unsigned short* W2T   = (unsigned short*)(ws + 65536);  // 64 KB
    unsigned short* W3T   = (unsigned short*)(ws + 131072); // 36 KB
    unsigned short* featb = (unsigned short*)(ws + 167936); // N*D bf16
    const size_t need = 167936 + (size_t)N * D * 2;
    const bool small_ok = (size_t)S * D * 4 <= 57344;

    if (ws_size >= need && small_ok && (N * D % 2048) == 0) {
        const int nFeatBlk = N * D / 2048;     // 256 thr * 8 elem
        prep_kernel<<<nFeatBlk + 200 + S, 256, 0, stream>>>(
            features, Wself, Wneigh, W3, seeds, allnodes, mask, neigh,
            featb, W2T, W3T, srow, N, nFeatBlk, 1);
        sm_kernel<<<1, 256, 0, stream>>>(srow, S, snum, W1, smp);
        const int nTiles = (C + 15) / 16;
        fused_kernel<<<nTiles, 256, 0, stream>>>(cand, allnodes, mask, featb,
                                                 neigh, W2T, W3T, smp, Q, C);
    } else {
        // fallback: fp32 path; prep runs only the seed segment
        prep_kernel<<<S, 256, 0, stream>>>(
            features, Wself, Wneigh, W3, seeds, allnodes, mask, neigh,
            (unsigned short*)ws, (unsigned short*)ws, (unsigned short*)ws,
            srow, N, 0, 0);
        sm_kernel<<<1, 256, 0, stream>>>(srow, S, snum, W1, smp);
        const int nblk = (C + MCAND - 1) / MCAND;
        cand_kernel<<<nblk, 128, 0, stream>>>(cand, allnodes, mask, features,
                                              neigh, Wself, Wneigh, W3, smp, Q, C);
    }
}

// Round 6
// 96.194 us; speedup vs baseline: 1.5209x; 1.1310x over previous
//
#include <hip/hip_runtime.h>

#define D     128
#define DP1   129
#define KN    10
#define GSZ   100000.0f

typedef __attribute__((ext_vector_type(8))) short bf16x8;
typedef __attribute__((ext_vector_type(4))) float f32x4;
typedef __attribute__((ext_vector_type(4))) unsigned uintx4;

#define MFMA16(a, b, c) __builtin_amdgcn_mfma_f32_16x16x32_bf16((a), (b), (c), 0, 0, 0)

__device__ __forceinline__ float sigmoidf_(float x) {
    return 1.0f / (1.0f + __expf(-x));
}
__device__ __forceinline__ unsigned short f2bf(float f) {
    unsigned u = __float_as_uint(f);
    u += 0x7FFFu + ((u >> 16) & 1u);          // RNE
    return (unsigned short)(u >> 16);
}
__device__ __forceinline__ unsigned pack2bf(float lo, float hi) {
    return (unsigned)f2bf(lo) | ((unsigned)f2bf(hi) << 16);
}

// ---------------------------------------------------------------------------
// Prep kernel: three segments by blockIdx.
//   [0, nFeatBlk)        : features fp32 -> bf16 (featb)
//   [nFeatBlk, +doW*200) : W2T[128][256], W3T[144][128] bf16 transpose
//   [.., +S)             : per-seed SAGE row -> srow[b][128]
// ---------------------------------------------------------------------------
__global__ __launch_bounds__(256) void prep_kernel(
    const float* __restrict__ features,
    const float* __restrict__ Wself, const float* __restrict__ Wneigh,
    const float* __restrict__ W3,
    const int*   __restrict__ seeds,
    const int*   __restrict__ all_nodes,
    const float* __restrict__ mask,
    const int*   __restrict__ neigh,
    unsigned short* __restrict__ featb,
    unsigned short* __restrict__ W2T,
    unsigned short* __restrict__ W3T,
    float*          __restrict__ srow,
    int N, int nFeatBlk, int doW)
{
    int b = blockIdx.x;
    const int t = threadIdx.x;

    if (b < nFeatBlk) {
        const int i = b * 256 + t;                  // bf16x8 chunk
        const int n8 = N * D / 8;
        if (i < n8) {
            const float4 a = *(const float4*)(features + (size_t)i * 8);
            const float4 c = *(const float4*)(features + (size_t)i * 8 + 4);
            bf16x8 v;
            v[0] = (short)f2bf(a.x); v[1] = (short)f2bf(a.y);
            v[2] = (short)f2bf(a.z); v[3] = (short)f2bf(a.w);
            v[4] = (short)f2bf(c.x); v[5] = (short)f2bf(c.y);
            v[6] = (short)f2bf(c.z); v[7] = (short)f2bf(c.w);
            *(bf16x8*)(featb + (size_t)i * 8) = v;
        }
        return;
    }
    b -= nFeatBlk;

    if (b < doW * 200) {
        const int u = b * 256 + t;
        if (u < 128 * 256) {
            int n = u >> 8, k = u & 255;
            float v = (k < 128) ? Wself[k * 128 + n] : Wneigh[(k - 128) * 128 + n];
            W2T[n * 256 + k] = f2bf(v);
        } else {
            int w = u - 128 * 256;
            if (w < 144 * 128) {
                int j = w >> 7, k = w & 127;
                float v = (j < DP1) ? W3[k * DP1 + j] : 0.0f;
                W3T[j * 128 + k] = f2bf(v);
            }
        }
        return;
    }
    b -= doW * 200;

    // ---- seed segment (block b = seed slot) ----
    const int node = seeds[b];
    if (node >= N || node < 0) {                   // pad row -> zero
        if (t < D) srow[b * D + t] = 0.f;
        return;
    }
    __shared__ float xs[D], nb[D];
    if (t < D) {
        xs[t] = features[(size_t)all_nodes[node] * D + t];
        float a = 0.f;
        #pragma unroll
        for (int k = 0; k < KN; ++k)
            a += features[(size_t)neigh[node * KN + k] * D + t];
        nb[t] = a * (1.0f / KN);
    }
    __syncthreads();
    if (t < D) {
        float h = 0.f;
        #pragma unroll 4
        for (int dp = 0; dp < D; ++dp)
            h = fmaf(xs[dp], Wself[dp * D + t], fmaf(nb[dp], Wneigh[dp * D + t], h));
        srow[b * D + t] = fmaxf(h, 0.f) * mask[node];
    }
}

// ---------------------------------------------------------------------------
// sm kernel: smp[144] = sigmoid((sum_b srow[b] / num) @ W1), zero-padded.
// Row sum parallelized over 2 half-warps per column.
// ---------------------------------------------------------------------------
__global__ __launch_bounds__(256) void sm_kernel(
    const float* __restrict__ srow, int S,
    const float* __restrict__ snum,
    const float* __restrict__ W1,
    float*       __restrict__ smp)
{
    __shared__ float ps[2][D];
    __shared__ float s[D];
    const int t   = threadIdx.x;
    const int col = t & 127;
    const int hf  = t >> 7;
    float a = 0.f;
    for (int b = hf; b < S; b += 2) a += srow[b * D + col];
    ps[hf][col] = a;
    __syncthreads();
    if (t < D) s[t] = (ps[0][t] + ps[1][t]) / snum[0];
    __syncthreads();
    if (t < DP1) {
        float acc = 0.f;
        #pragma unroll 4
        for (int dp = 0; dp < D; ++dp)
            acc = fmaf(s[dp], W1[dp * DP1 + t], acc);
        smp[t] = sigmoidf_(acc);
    } else if (t < 144) {
        smp[t] = 0.0f;
    }
}

// ---------------------------------------------------------------------------
// Fused candidate kernel.
// 16 cands/block, 4 waves. Gather: 16-lane group per candidate, 16 B/lane
// bf16x8 loads (1 KB per wave instruction, 11 instrs/wave). GEMM: split
// across all 4 waves (GEMM1: 2 n-tiles each; GEMM2: 2-3 j-tiles each),
// h exchanged via the shared LDS tile, final dot via LDS reduce.
// ---------------------------------------------------------------------------
__global__ __launch_bounds__(256) void fused_kernel(
    const int*            __restrict__ cand,
    const int*            __restrict__ all_nodes,
    const float*          __restrict__ mask,
    const unsigned short* __restrict__ featb,
    const int*            __restrict__ neigh,
    const unsigned short* __restrict__ W2T,
    const unsigned short* __restrict__ W3T,
    const float*          __restrict__ smp,
    float*                __restrict__ Q,
    int C)
{
    __shared__ unsigned short tile[16][256];
    __shared__ float msk[16];
    __shared__ float qred[4][16];

    const int lane  = threadIdx.x & 63;
    const int wv    = threadIdx.x >> 6;
    const int cbase = blockIdx.x * 16;

    const int L   = lane & 15;        // position within 16-lane group
    const int grp = lane >> 4;        // group = candidate slot within wave
    const int m   = wv * 4 + grp;     // tile row 0..15

    // ---- gather: group owns candidate m; lane loads 16 B of each row ----
    {
        const int cc  = cbase + m;
        const int nd  = cand[(cc < C) ? cc : 0];
        const int fr  = all_nodes[nd];
        if (L == 0) msk[m] = (cc < C) ? mask[nd] : 0.f;

        int rix[KN];
        #pragma unroll
        for (int k = 0; k < KN; ++k) rix[k] = neigh[nd * KN + k];

        const uintx4 xv = *(const uintx4*)(featb + (size_t)fr * D + L * 8);

        float a8[8];
        #pragma unroll
        for (int i = 0; i < 8; ++i) a8[i] = 0.f;

        #pragma unroll
        for (int k = 0; k < KN; ++k) {
            const uintx4 v = *(const uintx4*)(featb + (size_t)rix[k] * D + L * 8);
            #pragma unroll
            for (int i = 0; i < 4; ++i) {
                a8[2 * i]     += __uint_as_float(v[i] << 16);
                a8[2 * i + 1] += __uint_as_float(v[i] & 0xFFFF0000u);
            }
        }

        const int sw = (m & 7) << 3;
        unsigned short* tp = &tile[0][0];
        *(uintx4*)(tp + m * 256 + ((L * 8) ^ sw)) = xv;
        uintx4 nb;
        #pragma unroll
        for (int i = 0; i < 4; ++i)
            nb[i] = pack2bf(a8[2 * i] * (1.0f / KN), a8[2 * i + 1] * (1.0f / KN));
        *(uintx4*)(tp + m * 256 + ((128 + L * 8) ^ sw)) = nb;
    }

    const int g   = lane >> 4;
    const int n15 = lane & 15;
    const int swr = (n15 & 7) << 3;
    const unsigned short* tp = &tile[0][0];

    // prefetch ks=0 B fragments for GEMM1 (no LDS dependence -> overlaps barrier)
    bf16x8 bq0 = *(const bf16x8*)(W2T + ((wv * 2 + 0) * 16 + n15) * 256 + g * 8);
    bf16x8 bq1 = *(const bf16x8*)(W2T + ((wv * 2 + 1) * 16 + n15) * 256 + g * 8);

    __syncthreads();

    // ---- GEMM1: wave wv computes n-tiles {2wv, 2wv+1} ----
    bf16x8 afr[8];
    #pragma unroll
    for (int ks = 0; ks < 8; ++ks)
        afr[ks] = *(const bf16x8*)(tp + n15 * 256 + ((ks * 32 + g * 8) ^ swr));

    f32x4 acc1[2];
    acc1[0] = (f32x4){0.f, 0.f, 0.f, 0.f};
    acc1[1] = (f32x4){0.f, 0.f, 0.f, 0.f};

    acc1[0] = MFMA16(afr[0], bq0, acc1[0]);
    acc1[1] = MFMA16(afr[0], bq1, acc1[1]);
    #pragma unroll
    for (int ks = 1; ks < 8; ++ks) {
        #pragma unroll
        for (int i = 0; i < 2; ++i) {
            const bf16x8 b = *(const bf16x8*)(W2T + ((wv * 2 + i) * 16 + n15) * 256
                                              + ks * 32 + g * 8);
            acc1[i] = MFMA16(afr[ks], b, acc1[i]);
        }
    }

    // ---- relu * mask -> bf16 h back into tile (cols (2wv..2wv+1)*16) ----
    float mr[4];
    #pragma unroll
    for (int r = 0; r < 4; ++r) mr[r] = msk[g * 4 + r];

    #pragma unroll
    for (int i = 0; i < 2; ++i) {
        const f32x4 v = acc1[i];
        #pragma unroll
        for (int r = 0; r < 4; ++r) {
            const int m2 = g * 4 + r;
            tile[m2][(((wv * 2 + i) * 16 + n15)) ^ ((m2 & 7) << 3)] =
                f2bf(fmaxf(v[r], 0.f) * mr[r]);
        }
    }
    __syncthreads();

    // ---- GEMM2: wave wv computes j-tiles {wv, 4+wv} (+8 for wv==0) ----
    bf16x8 ah[4];
    #pragma unroll
    for (int ks = 0; ks < 4; ++ks)
        ah[ks] = *(const bf16x8*)(tp + n15 * 256 + ((ks * 32 + g * 8) ^ swr));

    const int jt0 = wv, jt1 = 4 + wv;
    f32x4 acc2[3];
    acc2[0] = (f32x4){0.f, 0.f, 0.f, 0.f};
    acc2[1] = (f32x4){0.f, 0.f, 0.f, 0.f};
    acc2[2] = (f32x4){0.f, 0.f, 0.f, 0.f};

    #pragma unroll
    for (int ks = 0; ks < 4; ++ks) {
        const bf16x8 b0 = *(const bf16x8*)(W3T + (jt0 * 16 + n15) * 128 + ks * 32 + g * 8);
        acc2[0] = MFMA16(ah[ks], b0, acc2[0]);
        const bf16x8 b1 = *(const bf16x8*)(W3T + (jt1 * 16 + n15) * 128 + ks * 32 + g * 8);
        acc2[1] = MFMA16(ah[ks], b1, acc2[1]);
        if (wv == 0) {
            const bf16x8 b2 = *(const bf16x8*)(W3T + (8 * 16 + n15) * 128 + ks * 32 + g * 8);
            acc2[2] = MFMA16(ah[ks], b2, acc2[2]);
        }
    }

    // ---- epilogue: partial dot over this wave's j-tiles ----
    float qp[4] = {0.f, 0.f, 0.f, 0.f};
    {
        const float sm0 = smp[jt0 * 16 + n15];
        const float sm1 = smp[jt1 * 16 + n15];
        #pragma unroll
        for (int r = 0; r < 4; ++r) {
            qp[r] += sm0 * sigmoidf_(acc2[0][r]);
            qp[r] += sm1 * sigmoidf_(acc2[1][r]);
        }
        if (wv == 0) {
            const float sm2 = smp[8 * 16 + n15];
            #pragma unroll
            for (int r = 0; r < 4; ++r)
                qp[r] += sm2 * sigmoidf_(acc2[2][r]);
        }
    }
    #pragma unroll
    for (int off = 8; off >= 1; off >>= 1)
        #pragma unroll
        for (int r = 0; r < 4; ++r)
            qp[r] += __shfl_xor(qp[r], off);

    if (n15 == 0) {
        #pragma unroll
        for (int r = 0; r < 4; ++r)
            qred[wv][g * 4 + r] = qp[r];
    }
    __syncthreads();

    const int t = threadIdx.x;
    if (t < 16) {
        const float s = qred[0][t] + qred[1][t] + qred[2][t] + qred[3][t];
        const int cr = cbase + t;
        if (cr < C) Q[cr] = (1.0f - s) * GSZ;
    }
}

// ---------------------------------------------------------------------------
// Fallback fp32 candidate kernel (used only if ws too small)
// ---------------------------------------------------------------------------
#define MCAND 8
__global__ __launch_bounds__(128) void cand_kernel(
    const int*   __restrict__ cand,
    const int*   __restrict__ all_nodes,
    const float* __restrict__ mask,
    const float* __restrict__ features,
    const int*   __restrict__ neigh,
    const float* __restrict__ Wself,
    const float* __restrict__ Wneigh,
    const float* __restrict__ W3,
    const float* __restrict__ sm,
    float*       __restrict__ Q,
    int C)
{
    const int c0 = blockIdx.x * MCAND;
    const int t  = threadIdx.x;

    __shared__ float z[2 * MCAND][D];
    __shared__ float h[MCAND][D];
    __shared__ float red1[MCAND][D];
    __shared__ float red2[MCAND][D];
    __shared__ float smsh[DP1];

    smsh[t] = sm[t];
    if (t == 0) smsh[D] = sm[D];

    float mskv[MCAND];
    #pragma unroll
    for (int m = 0; m < MCAND; ++m) {
        const int c    = c0 + m;
        const int node = (c < C) ? cand[c] : cand[0];
        mskv[m] = mask[node];
        z[m][t] = features[(size_t)all_nodes[node] * D + t];
        float a = 0.f;
        #pragma unroll
        for (int k = 0; k < KN; ++k)
            a += features[(size_t)neigh[node * KN + k] * D + t];
        z[MCAND + m][t] = a * (1.0f / KN);
    }
    __syncthreads();

    float acc[MCAND];
    #pragma unroll
    for (int m = 0; m < MCAND; ++m) acc[m] = 0.f;
    for (int dp = 0; dp < D; dp += 4) {
        const float ws0 = Wself[(dp + 0) * D + t];
        const float ws1 = Wself[(dp + 1) * D + t];
        const float ws2 = Wself[(dp + 2) * D + t];
        const float ws3 = Wself[(dp + 3) * D + t];
        const float wn0 = Wneigh[(dp + 0) * D + t];
        const float wn1 = Wneigh[(dp + 1) * D + t];
        const float wn2 = Wneigh[(dp + 2) * D + t];
        const float wn3 = Wneigh[(dp + 3) * D + t];
        #pragma unroll
        for (int m = 0; m < MCAND; ++m) {
            const float4 xv = *(const float4*)&z[m][dp];
            const float4 nv = *(const float4*)&z[MCAND + m][dp];
            float a = acc[m];
            a = fmaf(xv.x, ws0, a); a = fmaf(xv.y, ws1, a);
            a = fmaf(xv.z, ws2, a); a = fmaf(xv.w, ws3, a);
            a = fmaf(nv.x, wn0, a); a = fmaf(nv.y, wn1, a);
            a = fmaf(nv.z, wn2, a); a = fmaf(nv.w, wn3, a);
            acc[m] = a;
        }
    }
    #pragma unroll
    for (int m = 0; m < MCAND; ++m)
        h[m][t] = fmaxf(acc[m], 0.f) * mskv[m];
    __syncthreads();

    #pragma unroll
    for (int m = 0; m < MCAND; ++m) acc[m] = 0.f;
    for (int dp = 0; dp < D; dp += 4) {
        const float w0 = W3[(dp + 0) * DP1 + t];
        const float w1 = W3[(dp + 1) * DP1 + t];
        const float w2 = W3[(dp + 2) * DP1 + t];
        const float w3 = W3[(dp + 3) * DP1 + t];
        #pragma unroll
        for (int m = 0; m < MCAND; ++m) {
            const float4 hv = *(const float4*)&h[m][dp];
            float a = acc[m];
            a = fmaf(hv.x, w0, a); a = fmaf(hv.y, w1, a);
            a = fmaf(hv.z, w2, a); a = fmaf(hv.w, w3, a);
            acc[m] = a;
        }
    }

    const float w128 = W3[t * DP1 + D];
    const float smt  = smsh[t];
    #pragma unroll
    for (int m = 0; m < MCAND; ++m) {
        red1[m][t] = smt * sigmoidf_(acc[m]);
        red2[m][t] = h[m][t] * w128;
    }
    __syncthreads();

    for (int off = 64; off > 0; off >>= 1) {
        if (t < off) {
            #pragma unroll
            for (int m = 0; m < MCAND; ++m) {
                red1[m][t] += red1[m][t + off];
                red2[m][t] += red2[m][t + off];
            }
        }
        __syncthreads();
    }

    if (t < MCAND && (c0 + t) < C) {
        const float dot = red1[t][0] + smsh[D] * sigmoidf_(red2[t][0]);
        Q[c0 + t] = (1.0f - dot) * GSZ;
    }
}

// ---------------------------------------------------------------------------
extern "C" void kernel_launch(void* const* d_in, const int* in_sizes, int n_in,
                              void* d_out, int out_size, void* d_ws, size_t ws_size,
                              hipStream_t stream)
{
    const int*   seeds    = (const int*)  d_in[0];
    const float* snum     = (const float*)d_in[1];
    const int*   cand     = (const int*)  d_in[2];
    const int*   allnodes = (const int*)  d_in[3];
    const float* mask     = (const float*)d_in[4];
    const float* features = (const float*)d_in[5];
    const int*   neigh    = (const int*)  d_in[6];
    const float* Wself    = (const float*)d_in[7];
    const float* Wneigh   = (const float*)d_in[8];
    const float* W1       = (const float*)d_in[9];
    // d_in[10] = W2 : unused in reference
    const float* W3       = (const float*)d_in[11];

    float* Q = (float*)d_out;

    const int S = in_sizes[0];
    const int C = in_sizes[2];
    const int N = in_sizes[3];

    // ws layout (bytes)
    char* ws = (char*)d_ws;
    float*          srow  = (float*)ws;                     // S*128 f32 (<=56KB)
    float*          smp   = (float*)(ws + 57344);           // 144 f32
    unsigned short* W2T   = (unsigned short*)(ws + 65536);  // 64 KB
    unsigned short* W3T   = (unsigned short*)(ws + 131072); // 36 KB
    unsigned short* featb = (unsigned short*)(ws + 167936); // N*D bf16
    const size_t need = 167936 + (size_t)N * D * 2;
    const bool small_ok = (size_t)S * D * 4 <= 57344;

    if (ws_size >= need && small_ok && (N * D % 2048) == 0) {
        const int nFeatBlk = N * D / 2048;     // 256 thr * 8 elem
        prep_kernel<<<nFeatBlk + 200 + S, 256, 0, stream>>>(
            features, Wself, Wneigh, W3, seeds, allnodes, mask, neigh,
            featb, W2T, W3T, srow, N, nFeatBlk, 1);
        sm_kernel<<<1, 256, 0, stream>>>(srow, S, snum, W1, smp);
        const int nTiles = (C + 15) / 16;
        fused_kernel<<<nTiles, 256, 0, stream>>>(cand, allnodes, mask, featb,
                                                 neigh, W2T, W3T, smp, Q, C);
    } else {
        // fallback: fp32 path; prep runs only the seed segment
        prep_kernel<<<S, 256, 0, stream>>>(
            features, Wself, Wneigh, W3, seeds, allnodes, mask, neigh,
            (unsigned short*)ws, (unsigned short*)ws, (unsigned short*)ws,
            srow, N, 0, 0);
        sm_kernel<<<1, 256, 0, stream>>>(srow, S, snum, W1, smp);
        const int nblk = (C + MCAND - 1) / MCAND;
        cand_kernel<<<nblk, 128, 0, stream>>>(cand, allnodes, mask, features,
                                              neigh, Wself, Wneigh, W3, smp, Q, C);
    }
}